// Round 11
// baseline (558.798 us; speedup 1.0000x reference)
//
#include <hip/hip_runtime.h>
#include <hip/hip_bf16.h>
#include <math.h>

#define BDIM 1024
#define TDIM 4096
#define BT   16384   // B*T
#define KEXPN 8
#define RRANK 64
#define KR   512     // KEXPN*RRANK
#define KC   640     // per-branch extended width: 512 prod + 8 bias + 120 pad (5*128)
#define PW   1280    // concatenated P width (2*KC)
#define KRC  1024    // concatenated xV/yW width
#define NCH  64
#define TC   64      // T per chunk (NCH*TC == TDIM)

typedef __attribute__((ext_vector_type(8))) short bf16x8;
typedef __attribute__((ext_vector_type(4))) float f32x4;

typedef __attribute__((address_space(1))) char g_char;
typedef __attribute__((address_space(3))) char l_char;

// async 16B global->LDS: per-lane global addr, wave-uniform LDS base (+lane*16 by HW)
__device__ __forceinline__ void gload16(const short* g, short* lds_base_uniform) {
  __builtin_amdgcn_global_load_lds((const g_char*)(const char*)g,
                                   (l_char*)(char*)lds_base_uniform, 16, 0, 0);
}

// ---------------- elementwise conversion f32 -> bf16 (vectorized x4) ----------------
__global__ __launch_bounds__(256) void cvt_bf16_kernel(const float* __restrict__ in,
    __hip_bfloat16* __restrict__ out, long n4) {
  long id = (long)blockIdx.x * 256 + threadIdx.x;
  if (id >= n4) return;
  f32x4 v = ((const f32x4*)in)[id];
  long i = id * 4;
  out[i + 0] = __float2bfloat16(v[0]);
  out[i + 1] = __float2bfloat16(v[1]);
  out[i + 2] = __float2bfloat16(v[2]);
  out[i + 3] = __float2bfloat16(v[3]);
}

// ---------------- transpose-pack: out[e][d] = in[d][e], f32 -> bf16, D x D ----------------
__global__ __launch_bounds__(256) void transpose_pack_kernel(const float* __restrict__ in,
    __hip_bfloat16* __restrict__ out) {
  int id = blockIdx.x * 256 + threadIdx.x;   // 0 .. D*D
  if (id >= BDIM * BDIM) return;
  int d = id & (BDIM - 1);
  int e = id >> 10;
  out[(size_t)e * BDIM + d] = __float2bfloat16(in[(size_t)d * BDIM + e]);
}

// ---------------- pack V (K,D,R) -> Vmat[(k*64+r)][d] bf16 ----------------
__global__ __launch_bounds__(256) void pack_vmat_kernel(const float* __restrict__ V,
    __hip_bfloat16* __restrict__ out) {
  int id = blockIdx.x * 256 + threadIdx.x;     // 0 .. KR*BDIM
  if (id >= KR * BDIM) return;
  int d = id & (BDIM - 1);
  int kr = id >> 10;
  int k = kr >> 6, r = kr & 63;
  out[(size_t)kr * BDIM + d] = __float2bfloat16(V[((size_t)k * BDIM + d) * RRANK + r]);
}

// ---------------- pack U (K,D,R)+b (K,D) -> utT[c][e], c in [0,640) ----------------
__global__ __launch_bounds__(256) void pack_utT_kernel(const float* __restrict__ U,
    const float* __restrict__ bvec, __hip_bfloat16* __restrict__ out) {
  int id = blockIdx.x * 256 + threadIdx.x;     // 0 .. KC*BDIM
  if (id >= KC * BDIM) return;
  int e = id & (BDIM - 1);
  int c = id >> 10;
  float v = 0.0f;
  if (c < KR) {
    int k = c >> 6, r = c & 63;
    v = U[((size_t)k * BDIM + e) * RRANK + r];
  } else if (c < KR + KEXPN) {
    v = bvec[(size_t)(c - KR) * BDIM + e];
  }
  out[(size_t)c * BDIM + e] = __float2bfloat16(v);
}

// ================= 128^2 2-phase engine (small folds only) =================
template<int EPI>
__global__ __launch_bounds__(256) void gemm_nt(const __hip_bfloat16* __restrict__ A,
    const __hip_bfloat16* __restrict__ B, void* __restrict__ Cv, void* __restrict__ Cv2,
    int csplit, int ldc, int ldc2, const float* __restrict__ bias, int M, int N, int Kd) {
  __shared__ __align__(16) short Als[2][128 * 32];
  __shared__ __align__(16) short Bls[2][128 * 32];
  int nbx = gridDim.x;
  int nwg = nbx * gridDim.y;
  int bx = blockIdx.x, by = blockIdx.y;
  if ((nwg & 7) == 0) {
    int orig = by * nbx + bx;
    int cpx = nwg >> 3;
    int id = (orig & 7) * cpx + (orig >> 3);
    bx = id % nbx; by = id / nbx;
  }
  const short* As = (const short*)A;
  const short* Bs = (const short*)B;
  const int t  = threadIdx.x;
  const int w  = t >> 6;
  const int l  = t & 63;
  const int lr = l & 15;
  const int lk = l >> 4;
  const int wr = w >> 1;
  const int wc = w & 1;
  const int row0 = by * 128;
  const int col0 = bx * 128;
  const int srow = w * 16 + (l >> 2);
  const int scol = (l & 3) * 8;
  const short* ag0 = As + (size_t)(row0 + srow) * Kd + scol;
  const short* ag1 = As + (size_t)(row0 + 64 + srow) * Kd + scol;
  const short* bg0 = Bs + (size_t)(col0 + srow) * Kd + scol;
  const short* bg1 = Bs + (size_t)(col0 + 64 + srow) * Kd + scol;
  f32x4 acc[4][4] = {};
  const int nt = Kd / 32;
  auto stage = [&](int kt, int buf) {
    int k0 = kt * 32;
    gload16(ag0 + k0, &Als[buf][w * 512]);
    gload16(ag1 + k0, &Als[buf][2048 + w * 512]);
    gload16(bg0 + k0, &Bls[buf][w * 512]);
    gload16(bg1 + k0, &Bls[buf][2048 + w * 512]);
  };
  stage(0, 0);
  __syncthreads();
  int cur = 0;
  for (int kt = 0; kt < nt; ++kt) {
    if (kt + 1 < nt) stage(kt + 1, cur ^ 1);
    bf16x8 af[4], bfr[4];
    #pragma unroll
    for (int i = 0; i < 4; i++)
      af[i] = *(const bf16x8*)&Als[cur][(wr * 64 + i * 16 + lr) * 32 + lk * 8];
    #pragma unroll
    for (int j = 0; j < 4; j++)
      bfr[j] = *(const bf16x8*)&Bls[cur][(wc * 64 + j * 16 + lr) * 32 + lk * 8];
    #pragma unroll
    for (int i = 0; i < 4; i++)
      #pragma unroll
      for (int j = 0; j < 4; j++)
        acc[i][j] = __builtin_amdgcn_mfma_f32_16x16x32_bf16(af[i], bfr[j], acc[i][j], 0, 0, 0);
    __syncthreads();
    cur ^= 1;
  }
  #pragma unroll
  for (int i = 0; i < 4; i++)
    #pragma unroll
    for (int j = 0; j < 4; j++)
      #pragma unroll
      for (int g = 0; g < 4; g++) {
        int r = row0 + wr * 64 + i * 16 + lk * 4 + g;
        int c = col0 + wc * 64 + j * 16 + lr;
        float v = acc[i][j][g];
        void* dst = Cv;
        int cc = c, ld = ldc;
        if (c >= csplit) { dst = Cv2; cc = c - csplit; ld = ldc2; }
        size_t idx = (size_t)r * ld + cc;
        if (EPI == 0)      ((float*)dst)[idx] = v;
        else if (EPI == 1) ((__hip_bfloat16*)dst)[idx] = __float2bfloat16(v);
        else if (EPI == 2) {
          float xv = v + bias[cc];
          float gl = 0.5f * xv * (1.0f + erff(xv * 0.70710678118654752f));
          ((__hip_bfloat16*)dst)[idx] = __float2bfloat16(gl);
        } else {
          float s = 1.0f / (float)((r & (TDIM - 1)) + 1);
          ((float*)dst)[idx] = v * s;
        }
      }
}

// ================= 256^2 4-phase BK=64 engine (big GEMMs) — R10 schedule =================
template<int EPI>
__global__ __launch_bounds__(512, 2) void gemm_nt_256(const __hip_bfloat16* __restrict__ A,
    const __hip_bfloat16* __restrict__ B, void* __restrict__ Cv, void* __restrict__ Cv2,
    int csplit, int ldc, int ldc2, const float* __restrict__ bias, int M, int N, int Kd) {
  __shared__ __align__(16) short Als[2][2][256 * 32];   // [buf][kh] 64 KB
  __shared__ __align__(16) short Bls[2][2][256 * 32];   // 64 KB

  int nbx = gridDim.x;
  int nwg = nbx * gridDim.y;
  int bx = blockIdx.x, by = blockIdx.y;
  if ((nwg & 7) == 0) {
    int orig = by * nbx + bx;
    int cpx = nwg >> 3;
    int id = (orig & 7) * cpx + (orig >> 3);
    bx = id % nbx; by = id / nbx;
  }
  const short* As = (const short*)A;
  const short* Bs = (const short*)B;
  const int t  = threadIdx.x;      // 0..511
  const int w  = t >> 6;           // 0..7
  const int l  = t & 63;
  const int lr = l & 15;
  const int lk = l >> 4;
  const int wr = w >> 2;           // 0..1 (M half)
  const int wc = w & 3;            // 0..3 (N quarter)
  const int row0 = by * 256;
  const int col0 = bx * 256;

  const int srow  = t >> 2;                       // 0..127
  const int sslot = (t & 3) ^ ((srow >> 1) & 3);
  const short* agA0 = As + (size_t)(row0 + srow) * Kd + sslot * 8;
  const short* agA1 = As + (size_t)(row0 + 128 + srow) * Kd + sslot * 8;
  const short* bgB0 = Bs + (size_t)(col0 + srow) * Kd + sslot * 8;
  const short* bgB1 = Bs + (size_t)(col0 + 128 + srow) * Kd + sslot * 8;

  auto stageA = [&](int buf, int kh, int kt) {
    int k0 = kt * 64 + kh * 32;
    short* base = &Als[buf][kh][0];
    gload16(agA0 + k0, base + w * 512);
    gload16(agA1 + k0, base + 4096 + w * 512);
  };
  auto stageB = [&](int buf, int kh, int kt) {
    int k0 = kt * 64 + kh * 32;
    short* base = &Bls[buf][kh][0];
    gload16(bgB0 + k0, base + w * 512);
    gload16(bgB1 + k0, base + 4096 + w * 512);
  };

  int aoff[8], boff[4];
  #pragma unroll
  for (int mf = 0; mf < 8; ++mf) {
    int r = wr * 128 + mf * 16 + lr;
    aoff[mf] = r * 32 + ((lk ^ ((r >> 1) & 3)) << 3);
  }
  #pragma unroll
  for (int nf = 0; nf < 4; ++nf) {
    int r = wc * 64 + nf * 16 + lr;
    boff[nf] = r * 32 + ((lk ^ ((r >> 1) & 3)) << 3);
  }

  f32x4 acc[8][4] = {};
  const int NT = Kd >> 6;   // K-tiles of 64

  stageA(0, 0, 0); stageA(0, 1, 0); stageB(0, 0, 0); stageB(0, 1, 0);
  asm volatile("s_waitcnt vmcnt(0)" ::: "memory");
  __builtin_amdgcn_sched_barrier(0);
  __builtin_amdgcn_s_barrier();

  for (int kt = 0; kt < NT; ++kt) {
    const int buf = kt & 1, nb = buf ^ 1;
    const short* A0 = &Als[buf][0][0];
    const short* A1 = &Als[buf][1][0];
    const short* B0 = &Bls[buf][0][0];
    const short* B1 = &Bls[buf][1][0];
    const bool st = (kt + 1 < NT);
    bf16x8 af[4], bfr[4];

    // ---- phase 1: kh0, M-half 0 ----
    #pragma unroll
    for (int i = 0; i < 4; ++i) bfr[i] = *(const bf16x8*)&B0[boff[i]];
    #pragma unroll
    for (int i = 0; i < 4; ++i) af[i]  = *(const bf16x8*)&A0[aoff[i]];
    if (st) { stageA(nb, 0, kt + 1); stageA(nb, 1, kt + 1); }
    __builtin_amdgcn_s_barrier();
    __builtin_amdgcn_s_setprio(1);
    #pragma unroll
    for (int i = 0; i < 4; ++i)
      #pragma unroll
      for (int j = 0; j < 4; ++j)
        acc[i][j] = __builtin_amdgcn_mfma_f32_16x16x32_bf16(af[i], bfr[j], acc[i][j], 0, 0, 0);
    __builtin_amdgcn_s_setprio(0);
    __builtin_amdgcn_s_barrier();

    // ---- phase 2: kh0, M-half 1 (B reused) ----
    #pragma unroll
    for (int i = 0; i < 4; ++i) af[i] = *(const bf16x8*)&A0[aoff[4 + i]];
    if (st) { stageB(nb, 0, kt + 1); stageB(nb, 1, kt + 1); }
    __builtin_amdgcn_s_barrier();
    __builtin_amdgcn_s_setprio(1);
    #pragma unroll
    for (int i = 0; i < 4; ++i)
      #pragma unroll
      for (int j = 0; j < 4; ++j)
        acc[4 + i][j] = __builtin_amdgcn_mfma_f32_16x16x32_bf16(af[i], bfr[j], acc[4 + i][j], 0, 0, 0);
    __builtin_amdgcn_s_setprio(0);
    __builtin_amdgcn_s_barrier();

    // ---- phase 3: kh1, M-half 0 ----
    #pragma unroll
    for (int i = 0; i < 4; ++i) bfr[i] = *(const bf16x8*)&B1[boff[i]];
    #pragma unroll
    for (int i = 0; i < 4; ++i) af[i]  = *(const bf16x8*)&A1[aoff[i]];
    __builtin_amdgcn_s_barrier();
    __builtin_amdgcn_s_setprio(1);
    #pragma unroll
    for (int i = 0; i < 4; ++i)
      #pragma unroll
      for (int j = 0; j < 4; ++j)
        acc[i][j] = __builtin_amdgcn_mfma_f32_16x16x32_bf16(af[i], bfr[j], acc[i][j], 0, 0, 0);
    __builtin_amdgcn_s_setprio(0);
    __builtin_amdgcn_s_barrier();

    // ---- phase 4: kh1, M-half 1 ----
    #pragma unroll
    for (int i = 0; i < 4; ++i) af[i] = *(const bf16x8*)&A1[aoff[4 + i]];
    __builtin_amdgcn_s_barrier();
    __builtin_amdgcn_s_setprio(1);
    #pragma unroll
    for (int i = 0; i < 4; ++i)
      #pragma unroll
      for (int j = 0; j < 4; ++j)
        acc[4 + i][j] = __builtin_amdgcn_mfma_f32_16x16x32_bf16(af[i], bfr[j], acc[4 + i][j], 0, 0, 0);
    __builtin_amdgcn_s_setprio(0);
    asm volatile("s_waitcnt vmcnt(0)" ::: "memory");
    __builtin_amdgcn_sched_barrier(0);
    __builtin_amdgcn_s_barrier();
  }

  #pragma unroll
  for (int mf = 0; mf < 8; ++mf)
    #pragma unroll
    for (int nf = 0; nf < 4; ++nf)
      #pragma unroll
      for (int g = 0; g < 4; ++g) {
        int r = row0 + wr * 128 + mf * 16 + lk * 4 + g;
        int c = col0 + wc * 64 + nf * 16 + lr;
        float v = acc[mf][nf][g];
        void* dst = Cv;
        int cc = c, ld = ldc;
        if (c >= csplit) { dst = Cv2; cc = c - csplit; ld = ldc2; }
        size_t idx = (size_t)r * ld + cc;
        if (EPI == 0)      ((float*)dst)[idx] = v;
        else if (EPI == 1) ((__hip_bfloat16*)dst)[idx] = __float2bfloat16(v);
        else if (EPI == 2) {
          float xv = v + bias[cc];
          float gl = 0.5f * xv * (1.0f + erff(xv * 0.70710678118654752f));
          ((__hip_bfloat16*)dst)[idx] = __float2bfloat16(gl);
        } else {  // EPI == 4: divide by n_valid, f32 out
          float s = 1.0f / (float)((r & (TDIM - 1)) + 1);
          ((float*)dst)[idx] = v * s;
        }
      }
}

// ---------------- dual router: one launch covers Hf (y=0) and Hi (y=1) ----------------
__global__ __launch_bounds__(256) void router_kernel(const __hip_bfloat16* __restrict__ Hf,
    const __hip_bfloat16* __restrict__ Hi,
    const float* __restrict__ w2, const float* __restrict__ b2,
    const float* __restrict__ ebias, float* __restrict__ wgt_f, float* __restrict__ wgt_i) {
  const __hip_bfloat16* H = blockIdx.y ? Hi : Hf;
  float* wgt = blockIdx.y ? wgt_i : wgt_f;
  int wv = threadIdx.x >> 6;
  int l  = threadIdx.x & 63;
  int row = blockIdx.x * 4 + wv;
  if (row >= BT) return;
  float acc[KEXPN] = {};
  for (int i = 0; i < BDIM / 64; i++) {
    int h = i * 64 + l;
    float hv = __bfloat162float(H[(size_t)row * BDIM + h]);
    #pragma unroll
    for (int k = 0; k < KEXPN; k++) acc[k] += hv * w2[k * BDIM + h];
  }
  #pragma unroll
  for (int k = 0; k < KEXPN; k++)
    for (int off = 32; off; off >>= 1) acc[k] += __shfl_down(acc[k], off);
  if (l == 0) {
    float lg[KEXPN];
    float mx = -1e30f;
    #pragma unroll
    for (int k = 0; k < KEXPN; k++) { lg[k] = acc[k] + b2[k] + ebias[k]; mx = fmaxf(mx, lg[k]); }
    float s = 0.0f;
    #pragma unroll
    for (int k = 0; k < KEXPN; k++) { lg[k] = expf(lg[k] - mx); s += lg[k]; }
    float inv = 1.0f / s;
    #pragma unroll
    for (int k = 0; k < KEXPN; k++) wgt[(size_t)row * KEXPN + k] = lg[k] * inv;
  }
}

// ---------------- cumsum phase 1: per-chunk sums (yW is bf16) ----------------
__global__ __launch_bounds__(1024) void chunksum_kernel(const __hip_bfloat16* __restrict__ yW,
    float* __restrict__ S) {
  int j  = threadIdx.x;
  int ch = blockIdx.x;
  int b  = blockIdx.y;
  size_t base = ((size_t)b * TDIM + ch * TC) * KRC + j;
  float s = 0.0f;
  for (int t = 0; t < TC; t++) s += __bfloat162float(yW[base + (size_t)t * KRC]);
  S[((size_t)b * NCH + ch) * KRC + j] = s;
}

// ---------------- cumsum phase 2: exclusive scan of chunk sums (in place) ----------------
__global__ __launch_bounds__(1024) void scan_chunks_kernel(float* __restrict__ S) {
  int j = threadIdx.x;
  int b = blockIdx.x;
  float run = 0.0f;
  for (int ch = 0; ch < NCH; ch++) {
    size_t i = ((size_t)b * NCH + ch) * KRC + j;
    float v = S[i];
    S[i] = run;
    run += v;
  }
}

// ---------------- cumsum phase 3 + combine both branches -> Pcat (+ ext cols fused) ----------------
__global__ __launch_bounds__(1024) void combine_kernel(const __hip_bfloat16* __restrict__ yW,
    const float* __restrict__ S, const __hip_bfloat16* __restrict__ xV,
    const float* __restrict__ wf, const float* __restrict__ wi,
    const float* __restrict__ alphaPtr, __hip_bfloat16* __restrict__ P) {
  int j  = threadIdx.x;
  int ch = blockIdx.x;
  int b  = blockIdx.y;
  float alpha = alphaPtr[0];
  float scale = (j < KR) ? 1.0f : alpha;
  const float* wgt = (j < KR) ? wf : wi;
  int k = (j & (KR - 1)) >> 6;
  int pcol = (j < KR) ? j : j + 128;
  float run = S[((size_t)b * NCH + ch) * KRC + j];
  for (int t0 = 0; t0 < TC; t0++) {
    size_t row = (size_t)b * TDIM + ch * TC + t0;
    run += __bfloat162float(yW[row * KRC + j]);
    float p = __bfloat162float(xV[row * KRC + j]) * run * wgt[row * KEXPN + k] * scale;
    P[row * PW + pcol] = __float2bfloat16(p);
  }
  // fused ext-column fill: threads 0..255 write the 2x128 extension columns
  if (j < 256) {
    int half = j >> 7, jj = j & 127;
    int col = half ? (KC + KR + jj) : (KR + jj);
    const float* wg = half ? wi : wf;
    float sc = half ? alpha : 1.0f;
    for (int t0 = 0; t0 < TC; t0++) {
      size_t row = (size_t)b * TDIM + ch * TC + t0;
      float v = (jj < KEXPN) ? wg[row * KEXPN + jj] * sc : 0.0f;
      P[row * PW + col] = __float2bfloat16(v);
    }
  }
}

// ---------------- sentinel ----------------
__global__ __launch_bounds__(256) void fill_kernel(float* __restrict__ out, long n, float val) {
  long id = (long)blockIdx.x * 256 + threadIdx.x;
  if (id < n) out[id] = val;
}

extern "C" void kernel_launch(void* const* d_in, const int* in_sizes, int n_in,
                              void* d_out, int out_size, void* d_ws, size_t ws_size,
                              hipStream_t stream) {
  const float* x        = (const float*)d_in[0];
  const float* W_Q      = (const float*)d_in[1];
  const float* W_K      = (const float*)d_in[2];
  const float* W_O      = (const float*)d_in[3];
  const float* W_inv    = (const float*)d_in[4];
  const float* V_fwd    = (const float*)d_in[5];
  const float* W_fwd    = (const float*)d_in[6];
  const float* U_fwd    = (const float*)d_in[7];
  const float* b_fwd    = (const float*)d_in[8];
  const float* V_inv    = (const float*)d_in[9];
  const float* W_inv_e  = (const float*)d_in[10];
  const float* U_inv    = (const float*)d_in[11];
  const float* b_inv    = (const float*)d_in[12];
  const float* rw1      = (const float*)d_in[13];
  const float* rb1      = (const float*)d_in[14];
  const float* rw2      = (const float*)d_in[15];
  const float* rb2      = (const float*)d_in[16];
  const float* alphaPtr = (const float*)d_in[17];
  const float* ebias    = (const float*)d_in[18];

  char* ws = (char*)d_ws;
  size_t off = 0;
  auto alloc = [&](size_t sz) -> void* {
    void* p = ws + off;
    off += (sz + 255) & ~(size_t)255;
    return p;
  };

  // ---- weight-fold buffers (~28 MB) ----
  void* w1p   = alloc((size_t)2 * BDIM * BDIM * 2); // [w1 (rows 0-1023) | w1i = w1@Winv]
  void* w1pq  = alloc((size_t)2 * BDIM * BDIM * 2); // folded: [w1@WQ | w1@Winv@WQ]  (H weights)
  void* vfgq  = alloc((size_t)KRC * BDIM * 2);      // [vm_f (0-511) | Gq = vm_ie@Winv]
  void* wmgk  = alloc((size_t)KRC * BDIM * 2);      // [wm_f (0-511) | Gk = vm_i@Winv]
  void* xyw   = alloc((size_t)2 * BDIM * BDIM * 2); // folded: [vfgq@WQ (0-1023) | wmgk@WK]
  void* wo    = alloc((size_t)BDIM * BDIM * 2);
  void* winvT = alloc((size_t)BDIM * BDIM * 2);     // W_inv^T
  void* wqT   = alloc((size_t)BDIM * BDIM * 2);     // W_Q^T
  void* wkT   = alloc((size_t)BDIM * BDIM * 2);     // W_K^T
  void* vm_ie = alloc((size_t)KR * BDIM * 2);
  void* vm_i  = alloc((size_t)KR * BDIM * 2);
  void* utTf  = alloc((size_t)KC * BDIM * 2);
  void* utTi  = alloc((size_t)KC * BDIM * 2);
  void* Mcat  = alloc((size_t)BDIM * PW * 2);
  void* wgt_f = alloc((size_t)BT * KEXPN * 4);
  void* wgt_i = alloc((size_t)BT * KEXPN * 4);
  void* S     = alloc((size_t)4 * NCH * KRC * 4);
  // ---- big slots (5 x 33.5 MB) ----
  void* s_x   = alloc((size_t)BT * BDIM * 2);       // x bf16 (read by H-GEMM and xy-GEMM)
  void* Hf    = alloc((size_t)BT * BDIM * 2);       // H_fwd bf16; Pcat overlays Hf+Hi
  void* Hi    = alloc((size_t)BT * BDIM * 2);       // H_inv bf16 (adjacent to Hf)
  void* xVcat = alloc((size_t)BT * KRC * 2);        // bf16
  void* yWcat = alloc((size_t)BT * KRC * 2);        // bf16
  void* Pcat  = Hf;   // 41.9 MB bf16 spans Hf+Hi (dead after routers)

  if (off > ws_size) {
    fill_kernel<<<dim3((unsigned)((out_size + 255) / 256)), 256, 0, stream>>>(
        (float*)d_out, (long)out_size, (float)(off >> 20));
    return;
  }

  __hip_bfloat16* w1    = (__hip_bfloat16*)w1p;                       // rows 0-1023
  __hip_bfloat16* w1i   = w1 + (size_t)BDIM * BDIM;                   // rows 1024-2047
  __hip_bfloat16* vmf   = (__hip_bfloat16*)vfgq;                      // rows 0-511
  __hip_bfloat16* Gq    = vmf + (size_t)KR * BDIM;                    // rows 512-1023
  __hip_bfloat16* wmf   = (__hip_bfloat16*)wmgk;
  __hip_bfloat16* Gk    = wmf + (size_t)KR * BDIM;
  __hip_bfloat16* xywB  = (__hip_bfloat16*)xyw;                       // rows 0-1023: vmq'
  __hip_bfloat16* xywB2 = xywB + (size_t)BDIM * BDIM;                 // rows 1024-2047: wmG'

  auto cvt = [&](const float* in, void* out, long n) {
    long n4 = n / 4;
    cvt_bf16_kernel<<<dim3((unsigned)((n4 + 255) / 256)), dim3(256), 0, stream>>>(
        in, (__hip_bfloat16*)out, n4);
  };
  // 128^2 engine (folds)
  auto gemm2s = [&](const void* A, const void* Bm, void* C, void* C2, int csplit,
                    int ldc, int ldc2, int M, int N, int Kd, int epi, const float* bias) {
    dim3 g(N / 128, M / 128);
    if (epi == 0)      gemm_nt<0><<<g, 256, 0, stream>>>((const __hip_bfloat16*)A, (const __hip_bfloat16*)Bm, C, C2, csplit, ldc, ldc2, bias, M, N, Kd);
    else if (epi == 1) gemm_nt<1><<<g, 256, 0, stream>>>((const __hip_bfloat16*)A, (const __hip_bfloat16*)Bm, C, C2, csplit, ldc, ldc2, bias, M, N, Kd);
    else if (epi == 2) gemm_nt<2><<<g, 256, 0, stream>>>((const __hip_bfloat16*)A, (const __hip_bfloat16*)Bm, C, C2, csplit, ldc, ldc2, bias, M, N, Kd);
    else               gemm_nt<4><<<g, 256, 0, stream>>>((const __hip_bfloat16*)A, (const __hip_bfloat16*)Bm, C, C2, csplit, ldc, ldc2, bias, M, N, Kd);
  };
  auto gemms = [&](const void* A, const void* Bm, void* C, int M, int N, int Kd,
                   int epi, const float* bias) {
    gemm2s(A, Bm, C, C, N, N, N, M, N, Kd, epi, bias);
  };
  // 256^2 BK=64 engine (big GEMMs; M,N multiples of 256, K multiple of 64)
  auto gemm2b = [&](const void* A, const void* Bm, void* C, void* C2, int csplit,
                    int ldc, int ldc2, int M, int N, int Kd, int epi, const float* bias) {
    dim3 g(N / 256, M / 256);
    if (epi == 0)      gemm_nt_256<0><<<g, 512, 0, stream>>>((const __hip_bfloat16*)A, (const __hip_bfloat16*)Bm, C, C2, csplit, ldc, ldc2, bias, M, N, Kd);
    else if (epi == 1) gemm_nt_256<1><<<g, 512, 0, stream>>>((const __hip_bfloat16*)A, (const __hip_bfloat16*)Bm, C, C2, csplit, ldc, ldc2, bias, M, N, Kd);
    else if (epi == 2) gemm_nt_256<2><<<g, 512, 0, stream>>>((const __hip_bfloat16*)A, (const __hip_bfloat16*)Bm, C, C2, csplit, ldc, ldc2, bias, M, N, Kd);
    else               gemm_nt_256<4><<<g, 512, 0, stream>>>((const __hip_bfloat16*)A, (const __hip_bfloat16*)Bm, C, C2, csplit, ldc, ldc2, bias, M, N, Kd);
  };
  auto gemmb = [&](const void* A, const void* Bm, void* C, int M, int N, int Kd,
                   int epi, const float* bias) {
    gemm2b(A, Bm, C, C, N, N, N, M, N, Kd, epi, bias);
  };

  // ---- conversions & packing ----
  cvt(x,   s_x, (long)BT * BDIM);
  cvt(W_O, wo,  (long)BDIM * BDIM);
  cvt(rw1, w1,  (long)BDIM * BDIM);
  {
    dim3 gt((BDIM * BDIM + 255) / 256);
    transpose_pack_kernel<<<gt, 256, 0, stream>>>(W_inv, (__hip_bfloat16*)winvT);
    transpose_pack_kernel<<<gt, 256, 0, stream>>>(W_Q,   (__hip_bfloat16*)wqT);
    transpose_pack_kernel<<<gt, 256, 0, stream>>>(W_K,   (__hip_bfloat16*)wkT);
    dim3 g((KR * BDIM + 255) / 256);
    pack_vmat_kernel<<<g, 256, 0, stream>>>(V_fwd,   vmf);
    pack_vmat_kernel<<<g, 256, 0, stream>>>(W_fwd,   wmf);
    pack_vmat_kernel<<<g, 256, 0, stream>>>(W_inv_e, (__hip_bfloat16*)vm_ie);
    pack_vmat_kernel<<<g, 256, 0, stream>>>(V_inv,   (__hip_bfloat16*)vm_i);
    dim3 gu((KC * BDIM + 255) / 256);
    pack_utT_kernel<<<gu, 256, 0, stream>>>(U_fwd, b_fwd, (__hip_bfloat16*)utTf);
    pack_utT_kernel<<<gu, 256, 0, stream>>>(U_inv, b_inv, (__hip_bfloat16*)utTi);
  }

  // ---- weight folds (128^2 engine) ----
  // stage 1: W_inv folds
  gemms(w1,    winvT, w1i, BDIM, BDIM, BDIM, 1, nullptr);   // w1i = w1 @ W_inv
  gemms(vm_ie, winvT, Gq,  KR,   BDIM, BDIM, 1, nullptr);   // Gq  = vm_ie @ W_inv
  gemms(vm_i,  winvT, Gk,  KR,   BDIM, BDIM, 1, nullptr);   // Gk  = vm_i  @ W_inv
  // stage 2: W_Q / W_K folds (eliminate Q,K entirely)
  gemms(w1p,  wqT, w1pq,  2 * BDIM, BDIM, BDIM, 1, nullptr); // [w1;w1i] @ W_Q
  gemms(vfgq, wqT, xywB,  BDIM,     BDIM, BDIM, 1, nullptr); // [vm_f;Gq] @ W_Q
  gemms(wmgk, wkT, xywB2, BDIM,     BDIM, BDIM, 1, nullptr); // [wm_f;Gk] @ W_K
  // output-side fold: Mcat = W_O @ Ut (both branches), leading dim PW
  gemm2s(wo, utTf, Mcat, Mcat, KC, PW, PW, BDIM, KC, BDIM, 1, nullptr);
  gemm2s(wo, utTi, (__hip_bfloat16*)Mcat + KC, (__hip_bfloat16*)Mcat + KC,
         KC, PW, PW, BDIM, KC, BDIM, 1, nullptr);

  // ---- fused H directly from x: [H_fwd|H_inv] = gelu(x @ w1pq^T + b1) ----
  gemm2b(s_x, w1pq, Hf, Hi, BDIM, BDIM, BDIM, BT, 2 * BDIM, BDIM, 2, rb1);

  // ---- fused xV|yW directly from x: [xVcat|yWcat] = x @ xyw^T ----
  gemm2b(s_x, xyw, xVcat, yWcat, BDIM, BDIM, BDIM, BT, 2 * BDIM, BDIM, 1, nullptr);

  // ---- dual router ----
  router_kernel<<<dim3(BT / 4, 2), 256, 0, stream>>>((const __hip_bfloat16*)Hf,
      (const __hip_bfloat16*)Hi, rw2, rb2, ebias, (float*)wgt_f, (float*)wgt_i);

  // ---- causal cumsum + combine into Pcat (overlays Hf+Hi, dead after routers) ----
  dim3 gch(NCH, 4);
  chunksum_kernel<<<gch, 1024, 0, stream>>>((const __hip_bfloat16*)yWcat, (float*)S);
  scan_chunks_kernel<<<dim3(4), 1024, 0, stream>>>((float*)S);
  combine_kernel<<<gch, 1024, 0, stream>>>((const __hip_bfloat16*)yWcat, (const float*)S,
      (const __hip_bfloat16*)xVcat, (const float*)wgt_f, (const float*)wgt_i,
      alphaPtr, (__hip_bfloat16*)Pcat);

  // ---- single output GEMM: out = diag(1/n) * Pcat @ Mcat^T ----
  gemmb(Pcat, Mcat, d_out, BT, BDIM, PW, 4, nullptr);
}

// Round 12
// 464.012 us; speedup vs baseline: 1.2043x; 1.2043x over previous
//
#include <hip/hip_runtime.h>
#include <hip/hip_bf16.h>
#include <math.h>

#define BDIM 1024
#define TDIM 4096
#define BT   16384   // B*T
#define KEXPN 8
#define RRANK 64
#define KR   512     // KEXPN*RRANK
#define KC   640     // per-branch extended width: 512 prod + 8 bias + 120 pad
#define PW   1280    // concatenated P width (2*KC)
#define KRC  1024    // concatenated xV/yW width
#define NCH  64
#define TC   64      // T per chunk (NCH*TC == TDIM)

typedef __attribute__((ext_vector_type(8))) short bf16x8;
typedef __attribute__((ext_vector_type(4))) float f32x4;

typedef __attribute__((address_space(1))) char g_char;
typedef __attribute__((address_space(3))) char l_char;

// async 16B global->LDS: per-lane global addr, wave-uniform LDS base (+lane*16 by HW)
__device__ __forceinline__ void gload16(const short* g, short* lds_base_uniform) {
  __builtin_amdgcn_global_load_lds((const g_char*)(const char*)g,
                                   (l_char*)(char*)lds_base_uniform, 16, 0, 0);
}

// ---------------- elementwise conversion f32 -> bf16 (vectorized x4) ----------------
__global__ __launch_bounds__(256) void cvt_bf16_kernel(const float* __restrict__ in,
    __hip_bfloat16* __restrict__ out, long n4) {
  long id = (long)blockIdx.x * 256 + threadIdx.x;
  if (id >= n4) return;
  f32x4 v = ((const f32x4*)in)[id];
  long i = id * 4;
  out[i + 0] = __float2bfloat16(v[0]);
  out[i + 1] = __float2bfloat16(v[1]);
  out[i + 2] = __float2bfloat16(v[2]);
  out[i + 3] = __float2bfloat16(v[3]);
}

// ---------------- merged transpose-pack x3: out[e][d] = in[d][e], D x D ----------------
__global__ __launch_bounds__(256) void transpose3_kernel(
    const float* __restrict__ in0, __hip_bfloat16* __restrict__ o0,
    const float* __restrict__ in1, __hip_bfloat16* __restrict__ o1,
    const float* __restrict__ in2, __hip_bfloat16* __restrict__ o2) {
  int id = blockIdx.x * 256 + threadIdx.x;
  if (id >= BDIM * BDIM) return;
  const float* in = blockIdx.y == 0 ? in0 : (blockIdx.y == 1 ? in1 : in2);
  __hip_bfloat16* out = blockIdx.y == 0 ? o0 : (blockIdx.y == 1 ? o1 : o2);
  int d = id & (BDIM - 1);
  int e = id >> 10;
  out[(size_t)e * BDIM + d] = __float2bfloat16(in[(size_t)d * BDIM + e]);
}

// ---------------- merged pack V x4: (K,D,R) -> [(k*64+r)][d] bf16 ----------------
__global__ __launch_bounds__(256) void vmat4_kernel(
    const float* __restrict__ i0, __hip_bfloat16* __restrict__ o0,
    const float* __restrict__ i1, __hip_bfloat16* __restrict__ o1,
    const float* __restrict__ i2, __hip_bfloat16* __restrict__ o2,
    const float* __restrict__ i3, __hip_bfloat16* __restrict__ o3) {
  int id = blockIdx.x * 256 + threadIdx.x;
  if (id >= KR * BDIM) return;
  const float* V = blockIdx.y == 0 ? i0 : (blockIdx.y == 1 ? i1 : (blockIdx.y == 2 ? i2 : i3));
  __hip_bfloat16* out = blockIdx.y == 0 ? o0 : (blockIdx.y == 1 ? o1 : (blockIdx.y == 2 ? o2 : o3));
  int d = id & (BDIM - 1);
  int kr = id >> 10;
  int k = kr >> 6, r = kr & 63;
  out[(size_t)kr * BDIM + d] = __float2bfloat16(V[((size_t)k * BDIM + d) * RRANK + r]);
}

// ---------------- merged pack U+b x2 -> utT[c][e], c in [0,640) ----------------
__global__ __launch_bounds__(256) void utT2_kernel(
    const float* __restrict__ U0, const float* __restrict__ b0, __hip_bfloat16* __restrict__ o0,
    const float* __restrict__ U1, const float* __restrict__ b1, __hip_bfloat16* __restrict__ o1) {
  int id = blockIdx.x * 256 + threadIdx.x;
  if (id >= KC * BDIM) return;
  const float* U = blockIdx.y ? U1 : U0;
  const float* bvec = blockIdx.y ? b1 : b0;
  __hip_bfloat16* out = blockIdx.y ? o1 : o0;
  int e = id & (BDIM - 1);
  int c = id >> 10;
  float v = 0.0f;
  if (c < KR) {
    int k = c >> 6, r = c & 63;
    v = U[((size_t)k * BDIM + e) * RRANK + r];
  } else if (c < KR + KEXPN) {
    v = bvec[(size_t)(c - KR) * BDIM + e];
  }
  out[(size_t)c * BDIM + e] = __float2bfloat16(v);
}

// ================= 128^2 2-phase engine (weight folds), 3-way ROW-split epilogue =================
// C rows: r < rs1 -> C1 ; rs1 <= r < rs2 -> C2 (r-rs1) ; r >= rs2 -> C3 (r-rs2). bf16 out.
__global__ __launch_bounds__(256) void gemm_fold(const __hip_bfloat16* __restrict__ A,
    const __hip_bfloat16* __restrict__ B, void* __restrict__ C1, void* __restrict__ C2,
    void* __restrict__ C3, int rs1, int rs2, int ldc, int M, int N, int Kd) {
  __shared__ __align__(16) short Als[2][128 * 32];
  __shared__ __align__(16) short Bls[2][128 * 32];
  int nbx = gridDim.x;
  int nwg = nbx * gridDim.y;
  int bx = blockIdx.x, by = blockIdx.y;
  if ((nwg & 7) == 0) {
    int orig = by * nbx + bx;
    int cpx = nwg >> 3;
    int id = (orig & 7) * cpx + (orig >> 3);
    bx = id % nbx; by = id / nbx;
  }
  const short* As = (const short*)A;
  const short* Bs = (const short*)B;
  const int t  = threadIdx.x;
  const int w  = t >> 6;
  const int l  = t & 63;
  const int lr = l & 15;
  const int lk = l >> 4;
  const int wr = w >> 1;
  const int wc = w & 1;
  const int row0 = by * 128;
  const int col0 = bx * 128;
  const int srow = w * 16 + (l >> 2);
  const int scol = (l & 3) * 8;
  const short* ag0 = As + (size_t)(row0 + srow) * Kd + scol;
  const short* ag1 = As + (size_t)(row0 + 64 + srow) * Kd + scol;
  const short* bg0 = Bs + (size_t)(col0 + srow) * Kd + scol;
  const short* bg1 = Bs + (size_t)(col0 + 64 + srow) * Kd + scol;
  f32x4 acc[4][4] = {};
  const int nt = Kd / 32;
  auto stage = [&](int kt, int buf) {
    int k0 = kt * 32;
    gload16(ag0 + k0, &Als[buf][w * 512]);
    gload16(ag1 + k0, &Als[buf][2048 + w * 512]);
    gload16(bg0 + k0, &Bls[buf][w * 512]);
    gload16(bg1 + k0, &Bls[buf][2048 + w * 512]);
  };
  stage(0, 0);
  __syncthreads();
  int cur = 0;
  for (int kt = 0; kt < nt; ++kt) {
    if (kt + 1 < nt) stage(kt + 1, cur ^ 1);
    bf16x8 af[4], bfr[4];
    #pragma unroll
    for (int i = 0; i < 4; i++)
      af[i] = *(const bf16x8*)&Als[cur][(wr * 64 + i * 16 + lr) * 32 + lk * 8];
    #pragma unroll
    for (int j = 0; j < 4; j++)
      bfr[j] = *(const bf16x8*)&Bls[cur][(wc * 64 + j * 16 + lr) * 32 + lk * 8];
    #pragma unroll
    for (int i = 0; i < 4; i++)
      #pragma unroll
      for (int j = 0; j < 4; j++)
        acc[i][j] = __builtin_amdgcn_mfma_f32_16x16x32_bf16(af[i], bfr[j], acc[i][j], 0, 0, 0);
    __syncthreads();
    cur ^= 1;
  }
  #pragma unroll
  for (int i = 0; i < 4; i++)
    #pragma unroll
    for (int j = 0; j < 4; j++)
      #pragma unroll
      for (int g = 0; g < 4; g++) {
        int r = row0 + wr * 64 + i * 16 + lk * 4 + g;
        int c = col0 + wc * 64 + j * 16 + lr;
        void* dst = C1; int rr = r;
        if (r >= rs2)      { dst = C3; rr = r - rs2; }
        else if (r >= rs1) { dst = C2; rr = r - rs1; }
        ((__hip_bfloat16*)dst)[(size_t)rr * ldc + c] = __float2bfloat16(acc[i][j][g]);
      }
}

// ================= 256^2 4-phase BK=64 engine (big GEMMs) — R10 schedule =================
template<int EPI>
__global__ __launch_bounds__(512, 2) void gemm_nt_256(const __hip_bfloat16* __restrict__ A,
    const __hip_bfloat16* __restrict__ B, void* __restrict__ Cv, void* __restrict__ Cv2,
    int csplit, int ldc, int ldc2, const float* __restrict__ bias, int M, int N, int Kd) {
  __shared__ __align__(16) short Als[2][2][256 * 32];   // [buf][kh] 64 KB
  __shared__ __align__(16) short Bls[2][2][256 * 32];   // 64 KB

  int nbx = gridDim.x;
  int nwg = nbx * gridDim.y;
  int bx = blockIdx.x, by = blockIdx.y;
  if ((nwg & 7) == 0) {
    int orig = by * nbx + bx;
    int cpx = nwg >> 3;
    int id = (orig & 7) * cpx + (orig >> 3);
    bx = id % nbx; by = id / nbx;
  }
  const short* As = (const short*)A;
  const short* Bs = (const short*)B;
  const int t  = threadIdx.x;      // 0..511
  const int w  = t >> 6;           // 0..7
  const int l  = t & 63;
  const int lr = l & 15;
  const int lk = l >> 4;
  const int wr = w >> 2;           // 0..1 (M half)
  const int wc = w & 3;            // 0..3 (N quarter)
  const int row0 = by * 256;
  const int col0 = bx * 256;

  const int srow  = t >> 2;                       // 0..127
  const int sslot = (t & 3) ^ ((srow >> 1) & 3);
  const short* agA0 = As + (size_t)(row0 + srow) * Kd + sslot * 8;
  const short* agA1 = As + (size_t)(row0 + 128 + srow) * Kd + sslot * 8;
  const short* bgB0 = Bs + (size_t)(col0 + srow) * Kd + sslot * 8;
  const short* bgB1 = Bs + (size_t)(col0 + 128 + srow) * Kd + sslot * 8;

  auto stageA = [&](int buf, int kh, int kt) {
    int k0 = kt * 64 + kh * 32;
    short* base = &Als[buf][kh][0];
    gload16(agA0 + k0, base + w * 512);
    gload16(agA1 + k0, base + 4096 + w * 512);
  };
  auto stageB = [&](int buf, int kh, int kt) {
    int k0 = kt * 64 + kh * 32;
    short* base = &Bls[buf][kh][0];
    gload16(bgB0 + k0, base + w * 512);
    gload16(bgB1 + k0, base + 4096 + w * 512);
  };

  int aoff[8], boff[4];
  #pragma unroll
  for (int mf = 0; mf < 8; ++mf) {
    int r = wr * 128 + mf * 16 + lr;
    aoff[mf] = r * 32 + ((lk ^ ((r >> 1) & 3)) << 3);
  }
  #pragma unroll
  for (int nf = 0; nf < 4; ++nf) {
    int r = wc * 64 + nf * 16 + lr;
    boff[nf] = r * 32 + ((lk ^ ((r >> 1) & 3)) << 3);
  }

  f32x4 acc[8][4] = {};
  const int NT = Kd >> 6;   // K-tiles of 64

  stageA(0, 0, 0); stageA(0, 1, 0); stageB(0, 0, 0); stageB(0, 1, 0);
  asm volatile("s_waitcnt vmcnt(0)" ::: "memory");
  __builtin_amdgcn_sched_barrier(0);
  __builtin_amdgcn_s_barrier();

  for (int kt = 0; kt < NT; ++kt) {
    const int buf = kt & 1, nb = buf ^ 1;
    const short* A0 = &Als[buf][0][0];
    const short* A1 = &Als[buf][1][0];
    const short* B0 = &Bls[buf][0][0];
    const short* B1 = &Bls[buf][1][0];
    const bool st = (kt + 1 < NT);
    bf16x8 af[4], bfr[4];

    // ---- phase 1: kh0, M-half 0 ----
    #pragma unroll
    for (int i = 0; i < 4; ++i) bfr[i] = *(const bf16x8*)&B0[boff[i]];
    #pragma unroll
    for (int i = 0; i < 4; ++i) af[i]  = *(const bf16x8*)&A0[aoff[i]];
    if (st) { stageA(nb, 0, kt + 1); stageA(nb, 1, kt + 1); }
    __builtin_amdgcn_s_barrier();
    __builtin_amdgcn_s_setprio(1);
    #pragma unroll
    for (int i = 0; i < 4; ++i)
      #pragma unroll
      for (int j = 0; j < 4; ++j)
        acc[i][j] = __builtin_amdgcn_mfma_f32_16x16x32_bf16(af[i], bfr[j], acc[i][j], 0, 0, 0);
    __builtin_amdgcn_s_setprio(0);
    __builtin_amdgcn_s_barrier();

    // ---- phase 2: kh0, M-half 1 (B reused) ----
    #pragma unroll
    for (int i = 0; i < 4; ++i) af[i] = *(const bf16x8*)&A0[aoff[4 + i]];
    if (st) { stageB(nb, 0, kt + 1); stageB(nb, 1, kt + 1); }
    __builtin_amdgcn_s_barrier();
    __builtin_amdgcn_s_setprio(1);
    #pragma unroll
    for (int i = 0; i < 4; ++i)
      #pragma unroll
      for (int j = 0; j < 4; ++j)
        acc[4 + i][j] = __builtin_amdgcn_mfma_f32_16x16x32_bf16(af[i], bfr[j], acc[4 + i][j], 0, 0, 0);
    __builtin_amdgcn_s_setprio(0);
    __builtin_amdgcn_s_barrier();

    // ---- phase 3: kh1, M-half 0 ----
    #pragma unroll
    for (int i = 0; i < 4; ++i) bfr[i] = *(const bf16x8*)&B1[boff[i]];
    #pragma unroll
    for (int i = 0; i < 4; ++i) af[i]  = *(const bf16x8*)&A1[aoff[i]];
    __builtin_amdgcn_s_barrier();
    __builtin_amdgcn_s_setprio(1);
    #pragma unroll
    for (int i = 0; i < 4; ++i)
      #pragma unroll
      for (int j = 0; j < 4; ++j)
        acc[i][j] = __builtin_amdgcn_mfma_f32_16x16x32_bf16(af[i], bfr[j], acc[i][j], 0, 0, 0);
    __builtin_amdgcn_s_setprio(0);
    __builtin_amdgcn_s_barrier();

    // ---- phase 4: kh1, M-half 1 ----
    #pragma unroll
    for (int i = 0; i < 4; ++i) af[i] = *(const bf16x8*)&A1[aoff[4 + i]];
    __builtin_amdgcn_s_barrier();
    __builtin_amdgcn_s_setprio(1);
    #pragma unroll
    for (int i = 0; i < 4; ++i)
      #pragma unroll
      for (int j = 0; j < 4; ++j)
        acc[4 + i][j] = __builtin_amdgcn_mfma_f32_16x16x32_bf16(af[i], bfr[j], acc[4 + i][j], 0, 0, 0);
    __builtin_amdgcn_s_setprio(0);
    asm volatile("s_waitcnt vmcnt(0)" ::: "memory");
    __builtin_amdgcn_sched_barrier(0);
    __builtin_amdgcn_s_barrier();
  }

  #pragma unroll
  for (int mf = 0; mf < 8; ++mf)
    #pragma unroll
    for (int nf = 0; nf < 4; ++nf)
      #pragma unroll
      for (int g = 0; g < 4; ++g) {
        int r = row0 + wr * 128 + mf * 16 + lk * 4 + g;
        int c = col0 + wc * 64 + nf * 16 + lr;
        float v = acc[mf][nf][g];
        void* dst = Cv;
        int cc = c, ld = ldc;
        if (c >= csplit) { dst = Cv2; cc = c - csplit; ld = ldc2; }
        size_t idx = (size_t)r * ld + cc;
        if (EPI == 0)      ((float*)dst)[idx] = v;
        else if (EPI == 1) ((__hip_bfloat16*)dst)[idx] = __float2bfloat16(v);
        else if (EPI == 2) {
          float xv = v + bias[cc];
          float gl = 0.5f * xv * (1.0f + erff(xv * 0.70710678118654752f));
          ((__hip_bfloat16*)dst)[idx] = __float2bfloat16(gl);
        } else {  // EPI == 4: divide by n_valid, f32 out
          float s = 1.0f / (float)((r & (TDIM - 1)) + 1);
          ((float*)dst)[idx] = v * s;
        }
      }
}

// ---------------- dual router (vectorized bf16x8 loads) ----------------
__global__ __launch_bounds__(256) void router_kernel(const __hip_bfloat16* __restrict__ Hf,
    const __hip_bfloat16* __restrict__ Hi,
    const float* __restrict__ w2, const float* __restrict__ b2,
    const float* __restrict__ ebias, float* __restrict__ wgt_f, float* __restrict__ wgt_i) {
  const __hip_bfloat16* H = blockIdx.y ? Hi : Hf;
  float* wgt = blockIdx.y ? wgt_i : wgt_f;
  int wv = threadIdx.x >> 6;
  int l  = threadIdx.x & 63;
  int row = blockIdx.x * 4 + wv;
  if (row >= BT) return;
  const short* Hs = (const short*)H;
  float acc[KEXPN] = {};
  #pragma unroll
  for (int i = 0; i < BDIM / 512; i++) {      // 2 iterations, 8 values each
    int h = (i * 64 + l) * 8;
    bf16x8 hv = *(const bf16x8*)(Hs + (size_t)row * BDIM + h);
    #pragma unroll
    for (int j = 0; j < 8; j++) {
      unsigned int ui = ((unsigned int)(unsigned short)hv[j]) << 16;
      float xv = __uint_as_float(ui);
      #pragma unroll
      for (int k = 0; k < KEXPN; k++) acc[k] += xv * w2[k * BDIM + h + j];
    }
  }
  #pragma unroll
  for (int k = 0; k < KEXPN; k++)
    for (int off = 32; off; off >>= 1) acc[k] += __shfl_down(acc[k], off);
  if (l == 0) {
    float lg[KEXPN];
    float mx = -1e30f;
    #pragma unroll
    for (int k = 0; k < KEXPN; k++) { lg[k] = acc[k] + b2[k] + ebias[k]; mx = fmaxf(mx, lg[k]); }
    float s = 0.0f;
    #pragma unroll
    for (int k = 0; k < KEXPN; k++) { lg[k] = expf(lg[k] - mx); s += lg[k]; }
    float inv = 1.0f / s;
    #pragma unroll
    for (int k = 0; k < KEXPN; k++) wgt[(size_t)row * KEXPN + k] = lg[k] * inv;
  }
}

// ---------------- cumsum phase 1: per-chunk sums (yW is bf16) ----------------
__global__ __launch_bounds__(1024) void chunksum_kernel(const __hip_bfloat16* __restrict__ yW,
    float* __restrict__ S) {
  int j  = threadIdx.x;
  int ch = blockIdx.x;
  int b  = blockIdx.y;
  size_t base = ((size_t)b * TDIM + ch * TC) * KRC + j;
  float s = 0.0f;
  for (int t = 0; t < TC; t++) s += __bfloat162float(yW[base + (size_t)t * KRC]);
  S[((size_t)b * NCH + ch) * KRC + j] = s;
}

// ---------------- cumsum phase 2: exclusive scan of chunk sums (in place) ----------------
__global__ __launch_bounds__(1024) void scan_chunks_kernel(float* __restrict__ S) {
  int j = threadIdx.x;
  int b = blockIdx.x;
  float run = 0.0f;
  for (int ch = 0; ch < NCH; ch++) {
    size_t i = ((size_t)b * NCH + ch) * KRC + j;
    float v = S[i];
    S[i] = run;
    run += v;
  }
}

// ---------------- cumsum phase 3 + combine both branches -> Pcat (+ ext cols fused) ----------------
__global__ __launch_bounds__(1024) void combine_kernel(const __hip_bfloat16* __restrict__ yW,
    const float* __restrict__ S, const __hip_bfloat16* __restrict__ xV,
    const float* __restrict__ wf, const float* __restrict__ wi,
    const float* __restrict__ alphaPtr, __hip_bfloat16* __restrict__ P) {
  int j  = threadIdx.x;
  int ch = blockIdx.x;
  int b  = blockIdx.y;
  float alpha = alphaPtr[0];
  float scale = (j < KR) ? 1.0f : alpha;
  const float* wgt = (j < KR) ? wf : wi;
  int k = (j & (KR - 1)) >> 6;
  int pcol = (j < KR) ? j : j + 128;
  float run = S[((size_t)b * NCH + ch) * KRC + j];
  for (int t0 = 0; t0 < TC; t0++) {
    size_t row = (size_t)b * TDIM + ch * TC + t0;
    run += __bfloat162float(yW[row * KRC + j]);
    float p = __bfloat162float(xV[row * KRC + j]) * run * wgt[row * KEXPN + k] * scale;
    P[row * PW + pcol] = __float2bfloat16(p);
  }
  if (j < 256) {
    int half = j >> 7, jj = j & 127;
    int col = half ? (KC + KR + jj) : (KR + jj);
    const float* wg = half ? wi : wf;
    float sc = half ? alpha : 1.0f;
    for (int t0 = 0; t0 < TC; t0++) {
      size_t row = (size_t)b * TDIM + ch * TC + t0;
      float v = (jj < KEXPN) ? wg[row * KEXPN + jj] * sc : 0.0f;
      P[row * PW + col] = __float2bfloat16(v);
    }
  }
}

// ---------------- sentinel ----------------
__global__ __launch_bounds__(256) void fill_kernel(float* __restrict__ out, long n, float val) {
  long id = (long)blockIdx.x * 256 + threadIdx.x;
  if (id < n) out[id] = val;
}

extern "C" void kernel_launch(void* const* d_in, const int* in_sizes, int n_in,
                              void* d_out, int out_size, void* d_ws, size_t ws_size,
                              hipStream_t stream) {
  const float* x        = (const float*)d_in[0];
  const float* W_Q      = (const float*)d_in[1];
  const float* W_K      = (const float*)d_in[2];
  const float* W_O      = (const float*)d_in[3];
  const float* W_inv    = (const float*)d_in[4];
  const float* V_fwd    = (const float*)d_in[5];
  const float* W_fwd    = (const float*)d_in[6];
  const float* U_fwd    = (const float*)d_in[7];
  const float* b_fwd    = (const float*)d_in[8];
  const float* V_inv    = (const float*)d_in[9];
  const float* W_inv_e  = (const float*)d_in[10];
  const float* U_inv    = (const float*)d_in[11];
  const float* b_inv    = (const float*)d_in[12];
  const float* rw1      = (const float*)d_in[13];
  const float* rb1      = (const float*)d_in[14];
  const float* rw2      = (const float*)d_in[15];
  const float* rb2      = (const float*)d_in[16];
  const float* alphaPtr = (const float*)d_in[17];
  const float* ebias    = (const float*)d_in[18];

  char* ws = (char*)d_ws;
  size_t off = 0;
  auto alloc = [&](size_t sz) -> void* {
    void* p = ws + off;
    off += (sz + 255) & ~(size_t)255;
    return p;
  };

  const size_t RB = (size_t)BDIM * 2;          // bytes per 1024-col bf16 row
  // ---- fold buffers ----
  void* winvT = alloc((size_t)BDIM * RB);      // W_inv^T
  void* wqT   = alloc((size_t)BDIM * RB);      // W_Q^T
  void* wkT   = alloc((size_t)BDIM * RB);      // W_K^T
  void* wo    = alloc((size_t)BDIM * RB);      // W_O
  void* ST    = alloc((size_t)2048 * RB);      // [w1 | vm_ie | vm_i]  (stage-1 A)
  void* HXQ   = alloc((size_t)3072 * RB);      // [w1 | w1i | vm_f | Gq] (stage-2 A)
  void* XKA   = alloc((size_t)1024 * RB);      // [wm_f | Gk]
  void* HWq   = alloc((size_t)2048 * RB);      // H-GEMM B
  void* XYW   = alloc((size_t)2048 * RB);      // xy-GEMM B
  void* UTT   = alloc((size_t)1280 * RB);      // [utTf | utTi] stacked
  void* Mcat  = alloc((size_t)BDIM * PW * 2);  // out-GEMM B (ldc=PW)
  void* wgt_f = alloc((size_t)BT * KEXPN * 4);
  void* wgt_i = alloc((size_t)BT * KEXPN * 4);
  void* S     = alloc((size_t)4 * NCH * KRC * 4);
  // ---- big slots ----
  void* s_x   = alloc((size_t)BT * BDIM * 2);
  void* Hf    = alloc((size_t)BT * BDIM * 2);
  void* Hi    = alloc((size_t)BT * BDIM * 2);   // adjacent to Hf
  void* xVcat = alloc((size_t)BT * KRC * 2);
  void* yWcat = alloc((size_t)BT * KRC * 2);
  void* Pcat  = Hf;   // 41.9 MB spans Hf+Hi (dead after routers)

  if (off > ws_size) {
    fill_kernel<<<dim3((unsigned)((out_size + 255) / 256)), 256, 0, stream>>>(
        (float*)d_out, (long)out_size, (float)(off >> 20));
    return;
  }

  __hip_bfloat16* STp  = (__hip_bfloat16*)ST;
  __hip_bfloat16* HXQp = (__hip_bfloat16*)HXQ;
  __hip_bfloat16* XKAp = (__hip_bfloat16*)XKA;
  __hip_bfloat16* XYWp = (__hip_bfloat16*)XYW;
  __hip_bfloat16* UTTp = (__hip_bfloat16*)UTT;

  auto cvt = [&](const float* in, void* out, long n) {
    long n4 = n / 4;
    cvt_bf16_kernel<<<dim3((unsigned)((n4 + 255) / 256)), dim3(256), 0, stream>>>(
        in, (__hip_bfloat16*)out, n4);
  };
  auto fold = [&](const void* A, const void* Bm, void* C1, void* C2, void* C3,
                  int rs1, int rs2, int ldc, int M, int N, int Kd) {
    dim3 g(N / 128, M / 128);
    gemm_fold<<<g, 256, 0, stream>>>((const __hip_bfloat16*)A, (const __hip_bfloat16*)Bm,
        C1, C2, C3, rs1, rs2, ldc, M, N, Kd);
  };
  auto gemm2b = [&](const void* A, const void* Bm, void* C, void* C2, int csplit,
                    int ldc, int ldc2, int M, int N, int Kd, int epi, const float* bias) {
    dim3 g(N / 256, M / 256);
    if (epi == 1)      gemm_nt_256<1><<<g, 512, 0, stream>>>((const __hip_bfloat16*)A, (const __hip_bfloat16*)Bm, C, C2, csplit, ldc, ldc2, bias, M, N, Kd);
    else if (epi == 2) gemm_nt_256<2><<<g, 512, 0, stream>>>((const __hip_bfloat16*)A, (const __hip_bfloat16*)Bm, C, C2, csplit, ldc, ldc2, bias, M, N, Kd);
    else               gemm_nt_256<4><<<g, 512, 0, stream>>>((const __hip_bfloat16*)A, (const __hip_bfloat16*)Bm, C, C2, csplit, ldc, ldc2, bias, M, N, Kd);
  };

  // ---- prep (7 launches) ----
  cvt(x,   s_x, (long)BT * BDIM);
  cvt(W_O, wo,  (long)BDIM * BDIM);
  cvt(rw1, STp,  (long)BDIM * BDIM);                 // w1 -> ST rows 0-1023
  cvt(rw1, HXQp, (long)BDIM * BDIM);                 // w1 -> HXQ rows 0-1023
  transpose3_kernel<<<dim3((BDIM * BDIM + 255) / 256, 3), 256, 0, stream>>>(
      W_inv, (__hip_bfloat16*)winvT, W_Q, (__hip_bfloat16*)wqT, W_K, (__hip_bfloat16*)wkT);
  vmat4_kernel<<<dim3((KR * BDIM + 255) / 256, 4), 256, 0, stream>>>(
      V_fwd,   HXQp + (size_t)2048 * BDIM,           // vm_f -> HXQ rows 2048-2559
      W_fwd,   XKAp,                                 // wm_f -> XKA rows 0-511
      W_inv_e, STp + (size_t)1024 * BDIM,            // vm_ie -> ST rows 1024-1535
      V_inv,   STp + (size_t)1536 * BDIM);           // vm_i  -> ST rows 1536-2047
  utT2_kernel<<<dim3((KC * BDIM + 255) / 256, 2), 256, 0, stream>>>(
      U_fwd, b_fwd, UTTp, U_inv, b_inv, UTTp + (size_t)KC * BDIM);

  // ---- folds (4 launches) ----
  // stage 1: [w1; vm_ie; vm_i] @ W_inv -> rows 0-1023 w1i -> HXQ+1024; 1024-1535 Gq -> HXQ+2560; 1536-2047 Gk -> XKA+512
  fold(ST, winvT, HXQp + (size_t)1024 * BDIM, HXQp + (size_t)2560 * BDIM,
       XKAp + (size_t)512 * BDIM, 1024, 1536, BDIM, 2048, BDIM, BDIM);
  // stage 2a: [w1; w1i; vm_f; Gq] @ W_Q -> rows 0-2047 -> HWq; rows 2048-3071 -> XYW rows 0-1023
  fold(HXQ, wqT, HWq, XYWp, XYWp, 2048, 4096, BDIM, 3072, BDIM, BDIM);
  // stage 2b: [wm_f; Gk] @ W_K -> XYW rows 1024-2047
  fold(XKA, wkT, XYWp + (size_t)1024 * BDIM, nullptr, nullptr, 1024, 2048, BDIM, 1024, BDIM, BDIM);
  // Mcat: W_O @ [utTf; utTi] -> Mcat (1024 x 1280, ldc=PW)
  fold(wo, UTT, Mcat, nullptr, nullptr, 1024, 2048, PW, BDIM, PW, BDIM);

  // ---- big GEMMs (3 launches) ----
  gemm2b(s_x, HWq, Hf, Hi, BDIM, BDIM, BDIM, BT, 2 * BDIM, BDIM, 2, rb1);   // fused H
  gemm2b(s_x, XYW, xVcat, yWcat, BDIM, BDIM, BDIM, BT, 2 * BDIM, BDIM, 1, nullptr); // fused xV|yW

  // ---- dual router ----
  router_kernel<<<dim3(BT / 4, 2), 256, 0, stream>>>((const __hip_bfloat16*)Hf,
      (const __hip_bfloat16*)Hi, rw2, rb2, ebias, (float*)wgt_f, (float*)wgt_i);

  // ---- causal cumsum + combine into Pcat ----
  dim3 gch(NCH, 4);
  chunksum_kernel<<<gch, 1024, 0, stream>>>((const __hip_bfloat16*)yWcat, (float*)S);
  scan_chunks_kernel<<<dim3(4), 1024, 0, stream>>>((float*)S);
  combine_kernel<<<gch, 1024, 0, stream>>>((const __hip_bfloat16*)yWcat, (const float*)S,
      (const __hip_bfloat16*)xVcat, (const float*)wgt_f, (const float*)wgt_i,
      alphaPtr, (__hip_bfloat16*)Pcat);

  // ---- single output GEMM: out = diag(1/n) * Pcat @ Mcat^T ----
  gemm2b(Pcat, Mcat, d_out, d_out, BDIM, BDIM, BDIM, BT, BDIM, PW, 4, nullptr);
}

// Round 13
// 457.876 us; speedup vs baseline: 1.2204x; 1.0134x over previous
//
#include <hip/hip_runtime.h>
#include <hip/hip_bf16.h>
#include <math.h>

#define BDIM 1024
#define TDIM 4096
#define BT   16384   // B*T
#define KEXPN 8
#define RRANK 64
#define KR   512     // KEXPN*RRANK
#define PW2  1152    // packed P width: 512 prod_f + 512 prod_i + 8 wf + 8 wi + 112 pad
#define KRC  1024    // concatenated xV/yW width
#define NCH  64
#define TC   64      // T per chunk (NCH*TC == TDIM)

typedef __attribute__((ext_vector_type(8))) short bf16x8;
typedef __attribute__((ext_vector_type(4))) float f32x4;

typedef __attribute__((address_space(1))) char g_char;
typedef __attribute__((address_space(3))) char l_char;

// async 16B global->LDS: per-lane global addr, wave-uniform LDS base (+lane*16 by HW)
__device__ __forceinline__ void gload16(const short* g, short* lds_base_uniform) {
  __builtin_amdgcn_global_load_lds((const g_char*)(const char*)g,
                                   (l_char*)(char*)lds_base_uniform, 16, 0, 0);
}

// ---------------- elementwise conversion f32 -> bf16 (vectorized x4) ----------------
__global__ __launch_bounds__(256) void cvt_bf16_kernel(const float* __restrict__ in,
    __hip_bfloat16* __restrict__ out, long n4) {
  long id = (long)blockIdx.x * 256 + threadIdx.x;
  if (id >= n4) return;
  f32x4 v = ((const f32x4*)in)[id];
  long i = id * 4;
  out[i + 0] = __float2bfloat16(v[0]);
  out[i + 1] = __float2bfloat16(v[1]);
  out[i + 2] = __float2bfloat16(v[2]);
  out[i + 3] = __float2bfloat16(v[3]);
}

// ---------------- merged transpose-pack x3: out[e][d] = in[d][e], D x D ----------------
__global__ __launch_bounds__(256) void transpose3_kernel(
    const float* __restrict__ in0, __hip_bfloat16* __restrict__ o0,
    const float* __restrict__ in1, __hip_bfloat16* __restrict__ o1,
    const float* __restrict__ in2, __hip_bfloat16* __restrict__ o2) {
  int id = blockIdx.x * 256 + threadIdx.x;
  if (id >= BDIM * BDIM) return;
  const float* in = blockIdx.y == 0 ? in0 : (blockIdx.y == 1 ? in1 : in2);
  __hip_bfloat16* out = blockIdx.y == 0 ? o0 : (blockIdx.y == 1 ? o1 : o2);
  int d = id & (BDIM - 1);
  int e = id >> 10;
  out[(size_t)e * BDIM + d] = __float2bfloat16(in[(size_t)d * BDIM + e]);
}

// ---------------- merged pack V x4: (K,D,R) -> [(k*64+r)][d] bf16 ----------------
__global__ __launch_bounds__(256) void vmat4_kernel(
    const float* __restrict__ i0, __hip_bfloat16* __restrict__ o0,
    const float* __restrict__ i1, __hip_bfloat16* __restrict__ o1,
    const float* __restrict__ i2, __hip_bfloat16* __restrict__ o2,
    const float* __restrict__ i3, __hip_bfloat16* __restrict__ o3) {
  int id = blockIdx.x * 256 + threadIdx.x;
  if (id >= KR * BDIM) return;
  const float* V = blockIdx.y == 0 ? i0 : (blockIdx.y == 1 ? i1 : (blockIdx.y == 2 ? i2 : i3));
  __hip_bfloat16* out = blockIdx.y == 0 ? o0 : (blockIdx.y == 1 ? o1 : (blockIdx.y == 2 ? o2 : o3));
  int d = id & (BDIM - 1);
  int kr = id >> 10;
  int k = kr >> 6, r = kr & 63;
  out[(size_t)kr * BDIM + d] = __float2bfloat16(V[((size_t)k * BDIM + d) * RRANK + r]);
}

// ---------------- pack UTT[c][e], c in [0,1152): Uf-prod | Ui-prod | bf | bi | zeros ----------------
__global__ __launch_bounds__(256) void utt_pack_kernel(
    const float* __restrict__ Uf, const float* __restrict__ bf,
    const float* __restrict__ Ui, const float* __restrict__ bi,
    __hip_bfloat16* __restrict__ out) {
  int id = blockIdx.x * 256 + threadIdx.x;
  if (id >= PW2 * BDIM) return;
  int e = id & (BDIM - 1);
  int c = id >> 10;
  float v = 0.0f;
  if (c < KR) {
    int k = c >> 6, r = c & 63;
    v = Uf[((size_t)k * BDIM + e) * RRANK + r];
  } else if (c < 2 * KR) {
    int c2 = c - KR;
    int k = c2 >> 6, r = c2 & 63;
    v = Ui[((size_t)k * BDIM + e) * RRANK + r];
  } else if (c < 2 * KR + KEXPN) {
    v = bf[(size_t)(c - 2 * KR) * BDIM + e];
  } else if (c < 2 * KR + 2 * KEXPN) {
    v = bi[(size_t)(c - 2 * KR - KEXPN) * BDIM + e];
  }
  out[(size_t)c * BDIM + e] = __float2bfloat16(v);
}

// ================= 128^2 2-phase fold engine, TWO parallel partitions per launch =================
struct FoldArgs {
  const __hip_bfloat16* A; const __hip_bfloat16* B;
  void* C1; void* C2; void* C3;
  int rs1, rs2, ldc, M, N, Kd;
};

__device__ __forceinline__ void fold_body(const FoldArgs fa, int bx, int by,
                                          short* Als, short* Bls) {
  const short* As = (const short*)fa.A;
  const short* Bs = (const short*)fa.B;
  const int Kd = fa.Kd;
  const int t  = threadIdx.x;
  const int w  = t >> 6;
  const int l  = t & 63;
  const int lr = l & 15;
  const int lk = l >> 4;
  const int wr = w >> 1;
  const int wc = w & 1;
  const int row0 = by * 128;
  const int col0 = bx * 128;
  const int srow = w * 16 + (l >> 2);
  const int scol = (l & 3) * 8;
  const short* ag0 = As + (size_t)(row0 + srow) * Kd + scol;
  const short* ag1 = As + (size_t)(row0 + 64 + srow) * Kd + scol;
  const short* bg0 = Bs + (size_t)(col0 + srow) * Kd + scol;
  const short* bg1 = Bs + (size_t)(col0 + 64 + srow) * Kd + scol;
  f32x4 acc[4][4] = {};
  const int nt = Kd / 32;
  auto stage = [&](int kt, int buf) {
    int k0 = kt * 32;
    gload16(ag0 + k0, Als + buf * 4096 + w * 512);
    gload16(ag1 + k0, Als + buf * 4096 + 2048 + w * 512);
    gload16(bg0 + k0, Bls + buf * 4096 + w * 512);
    gload16(bg1 + k0, Bls + buf * 4096 + 2048 + w * 512);
  };
  stage(0, 0);
  __syncthreads();
  int cur = 0;
  for (int kt = 0; kt < nt; ++kt) {
    if (kt + 1 < nt) stage(kt + 1, cur ^ 1);
    bf16x8 af[4], bfr[4];
    #pragma unroll
    for (int i = 0; i < 4; i++)
      af[i] = *(const bf16x8*)&Als[cur * 4096 + (wr * 64 + i * 16 + lr) * 32 + lk * 8];
    #pragma unroll
    for (int j = 0; j < 4; j++)
      bfr[j] = *(const bf16x8*)&Bls[cur * 4096 + (wc * 64 + j * 16 + lr) * 32 + lk * 8];
    #pragma unroll
    for (int i = 0; i < 4; i++)
      #pragma unroll
      for (int j = 0; j < 4; j++)
        acc[i][j] = __builtin_amdgcn_mfma_f32_16x16x32_bf16(af[i], bfr[j], acc[i][j], 0, 0, 0);
    __syncthreads();
    cur ^= 1;
  }
  #pragma unroll
  for (int i = 0; i < 4; i++)
    #pragma unroll
    for (int j = 0; j < 4; j++)
      #pragma unroll
      for (int g = 0; g < 4; g++) {
        int r = row0 + wr * 64 + i * 16 + lk * 4 + g;
        int c = col0 + wc * 64 + j * 16 + lr;
        void* dst = fa.C1; int rr = r;
        if (r >= fa.rs2)      { dst = fa.C3; rr = r - fa.rs2; }
        else if (r >= fa.rs1) { dst = fa.C2; rr = r - fa.rs1; }
        ((__hip_bfloat16*)dst)[(size_t)rr * fa.ldc + c] = __float2bfloat16(acc[i][j][g]);
      }
}

__global__ __launch_bounds__(256) void gemm_fold2(FoldArgs fa0, FoldArgs fa1, int nblk0) {
  __shared__ __align__(16) short Als[2 * 128 * 32];
  __shared__ __align__(16) short Bls[2 * 128 * 32];
  int id = blockIdx.x;
  if (id < nblk0) {
    int nbx = fa0.N / 128;
    fold_body(fa0, id % nbx, id / nbx, Als, Bls);
  } else {
    int lid = id - nblk0;
    int nbx = fa1.N / 128;
    fold_body(fa1, lid % nbx, lid / nbx, Als, Bls);
  }
}

// ================= 256^2 4-phase BK=64 engine (big GEMMs) — R10 schedule =================
// EPI: 2 = bias+GELU->bf16 (2-seg), 4 = /n_valid->f32, 5 = 4-seg merged (gelu|gelu|bf16|bf16)
template<int EPI>
__global__ __launch_bounds__(512, 2) void gemm_nt_256(const __hip_bfloat16* __restrict__ A,
    const __hip_bfloat16* __restrict__ B, void* __restrict__ Cv, void* __restrict__ Cv2,
    void* __restrict__ Cv3, void* __restrict__ Cv4,
    int csplit, int ldc, int ldc2, const float* __restrict__ bias, int M, int N, int Kd) {
  __shared__ __align__(16) short Als[2][2][256 * 32];   // [buf][kh] 64 KB
  __shared__ __align__(16) short Bls[2][2][256 * 32];   // 64 KB

  int nbx = gridDim.x;
  int nwg = nbx * gridDim.y;
  int bx = blockIdx.x, by = blockIdx.y;
  if ((nwg & 7) == 0) {
    int orig = by * nbx + bx;
    int cpx = nwg >> 3;
    int id = (orig & 7) * cpx + (orig >> 3);
    bx = id % nbx; by = id / nbx;
  }
  const short* As = (const short*)A;
  const short* Bs = (const short*)B;
  const int t  = threadIdx.x;      // 0..511
  const int w  = t >> 6;           // 0..7
  const int l  = t & 63;
  const int lr = l & 15;
  const int lk = l >> 4;
  const int wr = w >> 2;           // 0..1 (M half)
  const int wc = w & 3;            // 0..3 (N quarter)
  const int row0 = by * 256;
  const int col0 = bx * 256;

  const int srow  = t >> 2;                       // 0..127
  const int sslot = (t & 3) ^ ((srow >> 1) & 3);
  const short* agA0 = As + (size_t)(row0 + srow) * Kd + sslot * 8;
  const short* agA1 = As + (size_t)(row0 + 128 + srow) * Kd + sslot * 8;
  const short* bgB0 = Bs + (size_t)(col0 + srow) * Kd + sslot * 8;
  const short* bgB1 = Bs + (size_t)(col0 + 128 + srow) * Kd + sslot * 8;

  auto stageA = [&](int buf, int kh, int kt) {
    int k0 = kt * 64 + kh * 32;
    short* base = &Als[buf][kh][0];
    gload16(agA0 + k0, base + w * 512);
    gload16(agA1 + k0, base + 4096 + w * 512);
  };
  auto stageB = [&](int buf, int kh, int kt) {
    int k0 = kt * 64 + kh * 32;
    short* base = &Bls[buf][kh][0];
    gload16(bgB0 + k0, base + w * 512);
    gload16(bgB1 + k0, base + 4096 + w * 512);
  };

  int aoff[8], boff[4];
  #pragma unroll
  for (int mf = 0; mf < 8; ++mf) {
    int r = wr * 128 + mf * 16 + lr;
    aoff[mf] = r * 32 + ((lk ^ ((r >> 1) & 3)) << 3);
  }
  #pragma unroll
  for (int nf = 0; nf < 4; ++nf) {
    int r = wc * 64 + nf * 16 + lr;
    boff[nf] = r * 32 + ((lk ^ ((r >> 1) & 3)) << 3);
  }

  f32x4 acc[8][4] = {};
  const int NT = Kd >> 6;   // K-tiles of 64

  stageA(0, 0, 0); stageA(0, 1, 0); stageB(0, 0, 0); stageB(0, 1, 0);
  asm volatile("s_waitcnt vmcnt(0)" ::: "memory");
  __builtin_amdgcn_sched_barrier(0);
  __builtin_amdgcn_s_barrier();

  for (int kt = 0; kt < NT; ++kt) {
    const int buf = kt & 1, nb = buf ^ 1;
    const short* A0 = &Als[buf][0][0];
    const short* A1 = &Als[buf][1][0];
    const short* B0 = &Bls[buf][0][0];
    const short* B1 = &Bls[buf][1][0];
    const bool st = (kt + 1 < NT);
    bf16x8 af[4], bfr[4];

    // ---- phase 1: kh0, M-half 0 ----
    #pragma unroll
    for (int i = 0; i < 4; ++i) bfr[i] = *(const bf16x8*)&B0[boff[i]];
    #pragma unroll
    for (int i = 0; i < 4; ++i) af[i]  = *(const bf16x8*)&A0[aoff[i]];
    if (st) { stageA(nb, 0, kt + 1); stageA(nb, 1, kt + 1); }
    __builtin_amdgcn_s_barrier();
    __builtin_amdgcn_s_setprio(1);
    #pragma unroll
    for (int i = 0; i < 4; ++i)
      #pragma unroll
      for (int j = 0; j < 4; ++j)
        acc[i][j] = __builtin_amdgcn_mfma_f32_16x16x32_bf16(af[i], bfr[j], acc[i][j], 0, 0, 0);
    __builtin_amdgcn_s_setprio(0);
    __builtin_amdgcn_s_barrier();

    // ---- phase 2: kh0, M-half 1 (B reused) ----
    #pragma unroll
    for (int i = 0; i < 4; ++i) af[i] = *(const bf16x8*)&A0[aoff[4 + i]];
    if (st) { stageB(nb, 0, kt + 1); stageB(nb, 1, kt + 1); }
    __builtin_amdgcn_s_barrier();
    __builtin_amdgcn_s_setprio(1);
    #pragma unroll
    for (int i = 0; i < 4; ++i)
      #pragma unroll
      for (int j = 0; j < 4; ++j)
        acc[4 + i][j] = __builtin_amdgcn_mfma_f32_16x16x32_bf16(af[i], bfr[j], acc[4 + i][j], 0, 0, 0);
    __builtin_amdgcn_s_setprio(0);
    __builtin_amdgcn_s_barrier();

    // ---- phase 3: kh1, M-half 0 ----
    #pragma unroll
    for (int i = 0; i < 4; ++i) bfr[i] = *(const bf16x8*)&B1[boff[i]];
    #pragma unroll
    for (int i = 0; i < 4; ++i) af[i]  = *(const bf16x8*)&A1[aoff[i]];
    __builtin_amdgcn_s_barrier();
    __builtin_amdgcn_s_setprio(1);
    #pragma unroll
    for (int i = 0; i < 4; ++i)
      #pragma unroll
      for (int j = 0; j < 4; ++j)
        acc[i][j] = __builtin_amdgcn_mfma_f32_16x16x32_bf16(af[i], bfr[j], acc[i][j], 0, 0, 0);
    __builtin_amdgcn_s_setprio(0);
    __builtin_amdgcn_s_barrier();

    // ---- phase 4: kh1, M-half 1 ----
    #pragma unroll
    for (int i = 0; i < 4; ++i) af[i] = *(const bf16x8*)&A1[aoff[4 + i]];
    __builtin_amdgcn_s_barrier();
    __builtin_amdgcn_s_setprio(1);
    #pragma unroll
    for (int i = 0; i < 4; ++i)
      #pragma unroll
      for (int j = 0; j < 4; ++j)
        acc[4 + i][j] = __builtin_amdgcn_mfma_f32_16x16x32_bf16(af[i], bfr[j], acc[4 + i][j], 0, 0, 0);
    __builtin_amdgcn_s_setprio(0);
    asm volatile("s_waitcnt vmcnt(0)" ::: "memory");
    __builtin_amdgcn_sched_barrier(0);
    __builtin_amdgcn_s_barrier();
  }

  #pragma unroll
  for (int mf = 0; mf < 8; ++mf)
    #pragma unroll
    for (int nf = 0; nf < 4; ++nf)
      #pragma unroll
      for (int g = 0; g < 4; ++g) {
        int r = row0 + wr * 128 + mf * 16 + lk * 4 + g;
        int c = col0 + wc * 64 + nf * 16 + lr;
        float v = acc[mf][nf][g];
        if (EPI == 5) {
          // 4-segment merged epilogue: seg 0,1 gelu->bf16; seg 2,3 plain bf16; all ldc=BDIM
          int seg = c >> 10;
          int cc = c & (BDIM - 1);
          void* dst = seg == 0 ? Cv : (seg == 1 ? Cv2 : (seg == 2 ? Cv3 : Cv4));
          if (seg < 2) {
            float xv = v + bias[cc];
            v = 0.5f * xv * (1.0f + erff(xv * 0.70710678118654752f));
          }
          ((__hip_bfloat16*)dst)[(size_t)r * BDIM + cc] = __float2bfloat16(v);
        } else {
          void* dst = Cv;
          int cc = c, ld = ldc;
          if (c >= csplit) { dst = Cv2; cc = c - csplit; ld = ldc2; }
          size_t idx = (size_t)r * ld + cc;
          if (EPI == 2) {
            float xv = v + bias[cc];
            float gl = 0.5f * xv * (1.0f + erff(xv * 0.70710678118654752f));
            ((__hip_bfloat16*)dst)[idx] = __float2bfloat16(gl);
          } else {  // EPI == 4: divide by n_valid, f32 out
            float s = 1.0f / (float)((r & (TDIM - 1)) + 1);
            ((float*)dst)[idx] = v * s;
          }
        }
      }
}

// ---------------- dual router (vectorized bf16x8 loads) ----------------
__global__ __launch_bounds__(256) void router_kernel(const __hip_bfloat16* __restrict__ Hf,
    const __hip_bfloat16* __restrict__ Hi,
    const float* __restrict__ w2, const float* __restrict__ b2,
    const float* __restrict__ ebias, float* __restrict__ wgt_f, float* __restrict__ wgt_i) {
  const __hip_bfloat16* H = blockIdx.y ? Hi : Hf;
  float* wgt = blockIdx.y ? wgt_i : wgt_f;
  int wv = threadIdx.x >> 6;
  int l  = threadIdx.x & 63;
  int row = blockIdx.x * 4 + wv;
  if (row >= BT) return;
  const short* Hs = (const short*)H;
  float acc[KEXPN] = {};
  #pragma unroll
  for (int i = 0; i < BDIM / 512; i++) {
    int h = (i * 64 + l) * 8;
    bf16x8 hv = *(const bf16x8*)(Hs + (size_t)row * BDIM + h);
    #pragma unroll
    for (int j = 0; j < 8; j++) {
      unsigned int ui = ((unsigned int)(unsigned short)hv[j]) << 16;
      float xv = __uint_as_float(ui);
      #pragma unroll
      for (int k = 0; k < KEXPN; k++) acc[k] += xv * w2[k * BDIM + h + j];
    }
  }
  #pragma unroll
  for (int k = 0; k < KEXPN; k++)
    for (int off = 32; off; off >>= 1) acc[k] += __shfl_down(acc[k], off);
  if (l == 0) {
    float lg[KEXPN];
    float mx = -1e30f;
    #pragma unroll
    for (int k = 0; k < KEXPN; k++) { lg[k] = acc[k] + b2[k] + ebias[k]; mx = fmaxf(mx, lg[k]); }
    float s = 0.0f;
    #pragma unroll
    for (int k = 0; k < KEXPN; k++) { lg[k] = expf(lg[k] - mx); s += lg[k]; }
    float inv = 1.0f / s;
    #pragma unroll
    for (int k = 0; k < KEXPN; k++) wgt[(size_t)row * KEXPN + k] = lg[k] * inv;
  }
}

// ---------------- cumsum phase 1: per-chunk sums (yW is bf16) ----------------
__global__ __launch_bounds__(1024) void chunksum_kernel(const __hip_bfloat16* __restrict__ yW,
    float* __restrict__ S) {
  int j  = threadIdx.x;
  int ch = blockIdx.x;
  int b  = blockIdx.y;
  size_t base = ((size_t)b * TDIM + ch * TC) * KRC + j;
  float s = 0.0f;
  for (int t = 0; t < TC; t++) s += __bfloat162float(yW[base + (size_t)t * KRC]);
  S[((size_t)b * NCH + ch) * KRC + j] = s;
}

// ---------------- cumsum phase 2: exclusive scan of chunk sums (in place) ----------------
__global__ __launch_bounds__(1024) void scan_chunks_kernel(float* __restrict__ S) {
  int j = threadIdx.x;
  int b = blockIdx.x;
  float run = 0.0f;
  for (int ch = 0; ch < NCH; ch++) {
    size_t i = ((size_t)b * NCH + ch) * KRC + j;
    float v = S[i];
    S[i] = run;
    run += v;
  }
}

// ---------------- cumsum phase 3 + combine both branches -> Pcat (+ ext cols fused) ----------------
// Pcat layout (width 1152): cols 0-511 prod_f, 512-1023 prod_i*alpha, 1024-1031 wf,
// 1032-1039 wi*alpha, 1040-1151 zero.
__global__ __launch_bounds__(1024) void combine_kernel(const __hip_bfloat16* __restrict__ yW,
    const float* __restrict__ S, const __hip_bfloat16* __restrict__ xV,
    const float* __restrict__ wf, const float* __restrict__ wi,
    const float* __restrict__ alphaPtr, __hip_bfloat16* __restrict__ P) {
  int j  = threadIdx.x;
  int ch = blockIdx.x;
  int b  = blockIdx.y;
  float alpha = alphaPtr[0];
  float scale = (j < KR) ? 1.0f : alpha;
  const float* wgt = (j < KR) ? wf : wi;
  int k = (j & (KR - 1)) >> 6;
  float run = S[((size_t)b * NCH + ch) * KRC + j];
  for (int t0 = 0; t0 < TC; t0++) {
    size_t row = (size_t)b * TDIM + ch * TC + t0;
    run += __bfloat162float(yW[row * KRC + j]);
    float p = __bfloat162float(xV[row * KRC + j]) * run * wgt[row * KEXPN + k] * scale;
    P[row * PW2 + j] = __float2bfloat16(p);
  }
  if (j < 128) {
    int col = KRC + j;
    for (int t0 = 0; t0 < TC; t0++) {
      size_t row = (size_t)b * TDIM + ch * TC + t0;
      float v = 0.0f;
      if (j < KEXPN)          v = wf[row * KEXPN + j];
      else if (j < 2 * KEXPN) v = wi[row * KEXPN + (j - KEXPN)] * alpha;
      P[row * PW2 + col] = __float2bfloat16(v);
    }
  }
}

// ---------------- sentinel ----------------
__global__ __launch_bounds__(256) void fill_kernel(float* __restrict__ out, long n, float val) {
  long id = (long)blockIdx.x * 256 + threadIdx.x;
  if (id < n) out[id] = val;
}

extern "C" void kernel_launch(void* const* d_in, const int* in_sizes, int n_in,
                              void* d_out, int out_size, void* d_ws, size_t ws_size,
                              hipStream_t stream) {
  const float* x        = (const float*)d_in[0];
  const float* W_Q      = (const float*)d_in[1];
  const float* W_K      = (const float*)d_in[2];
  const float* W_O      = (const float*)d_in[3];
  const float* W_inv    = (const float*)d_in[4];
  const float* V_fwd    = (const float*)d_in[5];
  const float* W_fwd    = (const float*)d_in[6];
  const float* U_fwd    = (const float*)d_in[7];
  const float* b_fwd    = (const float*)d_in[8];
  const float* V_inv    = (const float*)d_in[9];
  const float* W_inv_e  = (const float*)d_in[10];
  const float* U_inv    = (const float*)d_in[11];
  const float* b_inv    = (const float*)d_in[12];
  const float* rw1      = (const float*)d_in[13];
  const float* rb1      = (const float*)d_in[14];
  const float* rw2      = (const float*)d_in[15];
  const float* rb2      = (const float*)d_in[16];
  const float* alphaPtr = (const float*)d_in[17];
  const float* ebias    = (const float*)d_in[18];

  char* ws = (char*)d_ws;
  size_t off = 0;
  auto alloc = [&](size_t sz) -> void* {
    void* p = ws + off;
    off += (sz + 255) & ~(size_t)255;
    return p;
  };

  const size_t RB = (size_t)BDIM * 2;          // bytes per 1024-col bf16 row
  // ---- fold buffers ----
  void* winvT = alloc((size_t)BDIM * RB);      // W_inv^T
  void* wqT   = alloc((size_t)BDIM * RB);      // W_Q^T
  void* wkT   = alloc((size_t)BDIM * RB);      // W_K^T
  void* wo    = alloc((size_t)BDIM * RB);      // W_O
  void* ST    = alloc((size_t)2048 * RB);      // [w1 | vm_ie | vm_i]  (stage-1 A)
  void* HXQ   = alloc((size_t)3072 * RB);      // [w1 | w1i | vm_f | Gq] (stage-2a A)
  void* XKA   = alloc((size_t)1024 * RB);      // [wm_f | Gk]            (stage-2b A)
  void* BigB  = alloc((size_t)4096 * RB);      // merged big-GEMM B (4096 rows)
  void* UTT   = alloc((size_t)PW2 * RB);       // [Uf-prod | Ui-prod | bf | bi | 0]
  void* Mcat  = alloc((size_t)BDIM * PW2 * 2); // out-GEMM B (1024 x 1152)
  void* wgt_f = alloc((size_t)BT * KEXPN * 4);
  void* wgt_i = alloc((size_t)BT * KEXPN * 4);
  void* S     = alloc((size_t)4 * NCH * KRC * 4);
  // ---- big slots ----
  void* s_x   = alloc((size_t)BT * BDIM * 2);
  void* Hf    = alloc((size_t)BT * BDIM * 2);
  void* Hi    = alloc((size_t)BT * BDIM * 2);   // adjacent to Hf
  void* xVcat = alloc((size_t)BT * KRC * 2);
  void* yWcat = alloc((size_t)BT * KRC * 2);
  void* Pcat  = Hf;   // 37.7 MB bf16 spans Hf(+part of Hi), dead after routers

  if (off > ws_size) {
    fill_kernel<<<dim3((unsigned)((out_size + 255) / 256)), 256, 0, stream>>>(
        (float*)d_out, (long)out_size, (float)(off >> 20));
    return;
  }

  __hip_bfloat16* STp  = (__hip_bfloat16*)ST;
  __hip_bfloat16* HXQp = (__hip_bfloat16*)HXQ;
  __hip_bfloat16* XKAp = (__hip_bfloat16*)XKA;
  __hip_bfloat16* BigBp= (__hip_bfloat16*)BigB;
  __hip_bfloat16* UTTp = (__hip_bfloat16*)UTT;

  auto cvt = [&](const float* in, void* out, long n) {
    long n4 = n / 4;
    cvt_bf16_kernel<<<dim3((unsigned)((n4 + 255) / 256)), dim3(256), 0, stream>>>(
        in, (__hip_bfloat16*)out, n4);
  };
  auto gemm2b = [&](const void* A, const void* Bm, void* C, void* C2, void* C3, void* C4,
                    int csplit, int ldc, int ldc2, int M, int N, int Kd, int epi,
                    const float* bias) {
    dim3 g(N / 256, M / 256);
    if (epi == 2)      gemm_nt_256<2><<<g, 512, 0, stream>>>((const __hip_bfloat16*)A, (const __hip_bfloat16*)Bm, C, C2, C3, C4, csplit, ldc, ldc2, bias, M, N, Kd);
    else if (epi == 5) gemm_nt_256<5><<<g, 512, 0, stream>>>((const __hip_bfloat16*)A, (const __hip_bfloat16*)Bm, C, C2, C3, C4, csplit, ldc, ldc2, bias, M, N, Kd);
    else               gemm_nt_256<4><<<g, 512, 0, stream>>>((const __hip_bfloat16*)A, (const __hip_bfloat16*)Bm, C, C2, C3, C4, csplit, ldc, ldc2, bias, M, N, Kd);
  };

  // ---- prep (7 launches) ----
  cvt(x,   s_x, (long)BT * BDIM);
  cvt(W_O, wo,  (long)BDIM * BDIM);
  cvt(rw1, STp,  (long)BDIM * BDIM);                 // w1 -> ST rows 0-1023
  cvt(rw1, HXQp, (long)BDIM * BDIM);                 // w1 -> HXQ rows 0-1023
  transpose3_kernel<<<dim3((BDIM * BDIM + 255) / 256, 3), 256, 0, stream>>>(
      W_inv, (__hip_bfloat16*)winvT, W_Q, (__hip_bfloat16*)wqT, W_K, (__hip_bfloat16*)wkT);
  vmat4_kernel<<<dim3((KR * BDIM + 255) / 256, 4), 256, 0, stream>>>(
      V_fwd,   HXQp + (size_t)2048 * BDIM,           // vm_f -> HXQ rows 2048-2559
      W_fwd,   XKAp,                                 // wm_f -> XKA rows 0-511
      W_inv_e, STp + (size_t)1024 * BDIM,            // vm_ie -> ST rows 1024-1535
      V_inv,   STp + (size_t)1536 * BDIM);           // vm_i  -> ST rows 1536-2047
  utt_pack_kernel<<<dim3((PW2 * BDIM + 255) / 256), 256, 0, stream>>>(
      U_fwd, b_fwd, U_inv, b_inv, UTTp);

  // ---- folds: 2 launches, each with 2 parallel partitions ----
  // launch 1: stage-1 W_inv folds (128 blocks) || Mcat = W_O @ UTT^T (72 blocks)
  {
    FoldArgs f0 = { STp, (const __hip_bfloat16*)winvT,
                    HXQp + (size_t)1024 * BDIM, HXQp + (size_t)2560 * BDIM,
                    XKAp + (size_t)512 * BDIM, 1024, 1536, BDIM, 2048, BDIM, BDIM };
    FoldArgs f1 = { (const __hip_bfloat16*)wo, UTTp,
                    Mcat, nullptr, nullptr, 1 << 30, 1 << 30, PW2, BDIM, PW2, BDIM };
    int n0 = (f0.M / 128) * (f0.N / 128);   // 128
    int n1 = (f1.M / 128) * (f1.N / 128);   // 72
    gemm_fold2<<<dim3(n0 + n1), 256, 0, stream>>>(f0, f1, n0);
  }
  // launch 2: stage-2a [w1;w1i;vm_f;Gq]@W_Q -> BigB rows 0-3071 (192 blocks)
  //        || stage-2b [wm_f;Gk]@W_K -> BigB rows 3072-4095 (64 blocks)
  {
    FoldArgs f0 = { HXQp, (const __hip_bfloat16*)wqT,
                    BigBp, nullptr, nullptr, 1 << 30, 1 << 30, BDIM, 3072, BDIM, BDIM };
    FoldArgs f1 = { XKAp, (const __hip_bfloat16*)wkT,
                    BigBp + (size_t)3072 * BDIM, nullptr, nullptr, 1 << 30, 1 << 30,
                    BDIM, 1024, BDIM, BDIM };
    int n0 = (f0.M / 128) * (f0.N / 128);   // 192
    int n1 = (f1.M / 128) * (f1.N / 128);   // 64
    gemm_fold2<<<dim3(n0 + n1), 256, 0, stream>>>(f0, f1, n0);
  }

  // ---- ONE merged big GEMM: [Hf|Hi|xVcat|yWcat] = x @ BigB^T (N=4096, EPI=5) ----
  gemm2b(s_x, BigB, Hf, Hi, xVcat, yWcat, 0, 0, 0, BT, 4 * BDIM, BDIM, 5, rb1);

  // ---- dual router ----
  router_kernel<<<dim3(BT / 4, 2), 256, 0, stream>>>((const __hip_bfloat16*)Hf,
      (const __hip_bfloat16*)Hi, rw2, rb2, ebias, (float*)wgt_f, (float*)wgt_i);

  // ---- causal cumsum + combine into Pcat (overlays Hf/Hi, dead after routers) ----
  dim3 gch(NCH, 4);
  chunksum_kernel<<<gch, 1024, 0, stream>>>((const __hip_bfloat16*)yWcat, (float*)S);
  scan_chunks_kernel<<<dim3(4), 1024, 0, stream>>>((float*)S);
  combine_kernel<<<gch, 1024, 0, stream>>>((const __hip_bfloat16*)yWcat, (const float*)S,
      (const __hip_bfloat16*)xVcat, (const float*)wgt_f, (const float*)wgt_i,
      alphaPtr, (__hip_bfloat16*)Pcat);

  // ---- single output GEMM: out = diag(1/n) * Pcat @ Mcat^T (K=1152) ----
  gemm2b(Pcat, Mcat, d_out, d_out, nullptr, nullptr, BDIM, BDIM, BDIM,
         BT, BDIM, PW2, 4, nullptr);
}